// Round 4
// baseline (205.264 us; speedup 1.0000x reference)
//
#include <hip/hip_runtime.h>
#include <math.h>

#define BB 512
#define SS 128
#define KK 4
#define HH 128
#define DD 512   // K*H

typedef __attribute__((ext_vector_type(8))) short bf16x8;
typedef __attribute__((ext_vector_type(4))) float f32x4;

__device__ __forceinline__ unsigned short f2bf(float f) {
  unsigned u = __float_as_uint(f);
  unsigned r = u + 0x7fffu + ((u >> 16) & 1u);   // RNE (no NaNs in this data)
  return (unsigned short)(r >> 16);
}
__device__ __forceinline__ ushort4 f2bf4(float4 v) {
  ushort4 o; o.x = f2bf(v.x); o.y = f2bf(v.y); o.z = f2bf(v.z); o.w = f2bf(v.w);
  return o;
}
__device__ __forceinline__ float bfhi(unsigned u) { return __uint_as_float(u & 0xffff0000u); }
__device__ __forceinline__ float bflo(unsigned u) { return __uint_as_float(u << 16); }

// async global->LDS 16B copy: lds dest is wave-uniform base + lane*16
__device__ __forceinline__ void async_cp16(const void* g, void* l) {
  __builtin_amdgcn_global_load_lds(
      (const __attribute__((address_space(1))) unsigned int*)g,
      (__attribute__((address_space(3))) unsigned int*)l, 16, 0, 0);
}

// ---------------------------------------------------------------------------
// hat[b][k][s][h'] = sum_h item[b][s][h] * w[s][k*HH+h'][h]
// Barrier-free main loop: A tile (128b x 128h) cvt'd to bf16 in LDS behind a
// single barrier (reused by all 4 d-tiles); W fragments streamed
// global->register (32B f32 per fragment) and converted with plain f2bf
// (no inline asm — m240: compiler handles cvt; proven numerics). No Wl, no
// ds_writes, no per-step barriers: waves free-run, the unrolled fragment
// loads pipeline, epilogue stores drain in background.
// hat written with 16B-granule XOR (granule ^= s&15) so routing_k stages it
// linearly via global_load_lds and reads conflict-free.
// ---------------------------------------------------------------------------
__global__ __launch_bounds__(256) void einsum_mfma(
    const float* __restrict__ item,   // f32 [B][S][H]
    const float* __restrict__ w,      // f32 [S][D][H]
    unsigned short* __restrict__ hat) // bf16 [B][K][S][H], swizzled rows
{
  __shared__ unsigned short Al[128 * 128];     // 32 KB: rows = local b, 128 h
  const int s  = blockIdx.x;
  const int b0 = blockIdx.y * 128;
  const int t  = threadIdx.x;
  const int lane = t & 63, wvq = t >> 6;
  const int qm = wvq & 1, qn = wvq >> 1;
  const int n16 = lane & 15, kq = lane >> 4;

  const float* Abase = item + ((size_t)b0 * SS + s) * HH;  // + r*(SS*HH)
  const float* Wbase = w + (size_t)s * DD * HH;            // + (d0+r)*HH

  // ---- prologue: stage A tile (bf16, XOR-swizzled granules), one barrier ----
  const int ac = t & 31, ar0 = t >> 5;     // f4-col 0..31, row base 0..7
  #pragma unroll
  for (int c = 0; c < 2; ++c) {            // two chunks: cap VGPR pressure
    float4 ap[8];
    #pragma unroll
    for (int j = 0; j < 8; ++j)
      ap[j] = *(const float4*)(Abase + (size_t)(ar0 + 8 * (c * 8 + j)) * (SS * HH) + ac * 4);
    #pragma unroll
    for (int j = 0; j < 8; ++j) {
      const int r = ar0 + 8 * (c * 8 + j);
      const int lg = ac >> 1;                        // logical 16B granule
      *(ushort4*)&Al[r * 128 + ((lg ^ (r & 15)) * 8) + (ac & 1) * 4] = f2bf4(ap[j]);
    }
  }
  __syncthreads();                                   // the ONLY barrier

  const int sx = s & 15;
  for (int dt = 0; dt < 4; ++dt) {
    const int d0 = dt * 128;
    f32x4 acc[4][4] = {};
    #pragma unroll
    for (int kk4 = 0; kk4 < 4; ++kk4) {              // K in 32-chunks
      bf16x8 af[4], bfr[4];
      #pragma unroll
      for (int i = 0; i < 4; ++i) {
        const int ra = qm * 64 + i * 16 + n16;       // w rows (h')
        const float* wp = Wbase + (size_t)(d0 + ra) * HH + kk4 * 32 + kq * 8;
        float4 x = *(const float4*)wp;
        float4 y = *(const float4*)(wp + 4);
        union { ushort4 q[2]; bf16x8 v; } u;
        u.q[0] = f2bf4(x); u.q[1] = f2bf4(y);
        af[i] = u.v;
        const int rb = qn * 64 + i * 16 + n16;       // item rows (b)
        bfr[i] = *(const bf16x8*)&Al[rb * 128 + (((kk4 * 4 + kq) ^ (rb & 15)) * 8)];
      }
      #pragma unroll
      for (int i = 0; i < 4; ++i)
        #pragma unroll
        for (int j = 0; j < 4; ++j)
          acc[i][j] = __builtin_amdgcn_mfma_f32_16x16x32_bf16(af[i], bfr[j], acc[i][j], 0, 0, 0);
    }
    // epilogue d-tile dt: row = qm*64+i*16+kq*4+reg = h'; col = qn*64+j*16+n16 = b
    #pragma unroll
    for (int j = 0; j < 4; ++j) {
      const int b = b0 + qn * 64 + j * 16 + n16;
      char* orow = (char*)(hat + (((size_t)b * KK + dt) * SS + s) * HH);
      #pragma unroll
      for (int i = 0; i < 4; ++i) {
        const int h = qm * 64 + i * 16 + kq * 4;
        ushort4 o;
        o.x = f2bf(acc[i][j][0]); o.y = f2bf(acc[i][j][1]);
        o.z = f2bf(acc[i][j][2]); o.w = f2bf(acc[i][j][3]);
        *(ushort4*)(orow + ((((h >> 3) ^ sx) << 4) | ((h & 4) << 1))) = o;
      }
    }
  }
}

// ---------------------------------------------------------------------------
// Batch-axis softmax (legacy torch dim=0) + mask zeroing. Grid (S,K).
// ---------------------------------------------------------------------------
__global__ __launch_bounds__(256) void softmax_k(
    const float* __restrict__ cw, const float* __restrict__ mask,
    float* __restrict__ sw)
{
  __shared__ float rbuf[4];
  const int s = blockIdx.x, k = blockIdx.y, t = threadIdx.x;
  const size_t base = ((size_t)k * SS + s) * BB;
  float v0 = cw[base + t], v1 = cw[base + 256 + t];
  float m = fmaxf(v0, v1);
  #pragma unroll
  for (int o = 32; o; o >>= 1) m = fmaxf(m, __shfl_xor(m, o));
  if ((t & 63) == 0) rbuf[t >> 6] = m;
  __syncthreads();
  m = fmaxf(fmaxf(rbuf[0], rbuf[1]), fmaxf(rbuf[2], rbuf[3]));
  float e0 = expf(v0 - m), e1 = expf(v1 - m);
  float ssum = e0 + e1;
  #pragma unroll
  for (int o = 32; o; o >>= 1) ssum += __shfl_xor(ssum, o);
  __syncthreads();
  if ((t & 63) == 0) rbuf[t >> 6] = ssum;
  __syncthreads();
  float inv = 1.f / (rbuf[0] + rbuf[1] + rbuf[2] + rbuf[3]);
  float m0 = mask[(size_t)t * SS + s];
  float m1 = mask[(size_t)(t + 256) * SS + s];
  sw[base + t]       = (m0 == 0.f) ? 0.f : e0 * inv;
  sw[base + 256 + t] = (m1 == 0.f) ? 0.f : e1 * inv;
}

// ---------------------------------------------------------------------------
// One routing iteration per (b,k) — EXACT R2-verified structure. Per-WAVE
// staging: wave wv DMAs exactly the 8 KB of rows [32wv, 32wv+32) that its
// phase-1/phase-2 lanes consume, plus its own 32 sw values -> a per-wave
// s_waitcnt replaces the block-wide barrier.
//   mode 0: uniform sw from mask, cw  = delta
//   mode 1: sw from sw_in,        cw += delta
//   mode 2: sw from sw_in,        out = squash(cap)
// ---------------------------------------------------------------------------
__global__ __launch_bounds__(256) void routing_k(
    const unsigned short* __restrict__ hat, const float* __restrict__ mask,
    const float* __restrict__ sw_in, float* __restrict__ cw,
    float* __restrict__ out, int mode)
{
  __shared__ unsigned short hat_l[128 * 128];   // 32 KB, swizzled rows
  __shared__ float sw_l[128];
  __shared__ float4 red4[8][32];
  __shared__ float4 cq4[32];
  const int b = blockIdx.x, k = blockIdx.y, t = threadIdx.x;
  const int wv = t >> 6, lane = t & 63;

  // wave wv stages rows [32wv, 32wv+32) = bytes [wv*8192, +8192), linearly
  const char* slab = (const char*)(hat + ((size_t)b * KK + k) * SS * HH) + wv * 8192;
  char* ldst = (char*)hat_l + wv * 8192;
  #pragma unroll
  for (int j = 0; j < 8; ++j)
    async_cp16(slab + j * 1024 + lane * 16, ldst + j * 1024);

  if (lane < 32) {                               // own wave's sw values
    const int sv = wv * 32 + lane;
    sw_l[sv] = (mode == 0)
      ? ((mask[(size_t)b * SS + sv] == 0.f) ? 0.f : (1.f / 512.f))
      : sw_in[((size_t)k * SS + sv) * BB + b];
  }
  asm volatile("s_waitcnt vmcnt(0) lgkmcnt(0)" ::: "memory");  // own loads only

  // phase 1: cap[h] = sum_s sw[s]*hat[s][h]; sg = t>>5 -> own wave's rows
  {
    const int h4 = t & 31, sg = t >> 5;
    const char* base = (const char*)hat_l;
    float4 a = make_float4(0.f, 0.f, 0.f, 0.f);
    #pragma unroll 4
    for (int i = 0; i < 16; i++) {
      const int sr = sg * 16 + i;
      uint2 v = *(const uint2*)(base + sr * 256 +
                 ((((h4 >> 1) ^ (sr & 15)) << 4) | ((h4 & 1) << 3)));
      float wv2 = sw_l[sr];
      a.x = fmaf(wv2, bflo(v.x), a.x);
      a.y = fmaf(wv2, bfhi(v.x), a.y);
      a.z = fmaf(wv2, bflo(v.y), a.z);
      a.w = fmaf(wv2, bfhi(v.y), a.w);
    }
    red4[sg][h4] = a;
  }
  __syncthreads();

  if (t < 32) {
    float4 cap = red4[0][t];
    #pragma unroll
    for (int sg = 1; sg < 8; sg++) {
      float4 r = red4[sg][t];
      cap.x += r.x; cap.y += r.y; cap.z += r.z; cap.w += r.w;
    }
    float sq = cap.x * cap.x + cap.y * cap.y + cap.z * cap.z + cap.w * cap.w;
    #pragma unroll
    for (int o = 16; o; o >>= 1) sq += __shfl_xor(sq, o);
    const float n = sq;
    const float fac = n / (1.f + n) / sqrtf(n + 1e-9f);
    cap.x *= fac; cap.y *= fac; cap.z *= fac; cap.w *= fac;
    cq4[t] = cap;
    if (mode == 2)
      ((float4*)(out + ((size_t)b * KK + k) * HH))[t] = cap;
  }

  if (mode < 2) {
    __syncthreads();
    // phase 2: delta[s] = dot(hat[s][:], cq) — s = t>>1 -> own wave's rows
    const int sr = t >> 1, hh = t & 1;
    const char* rowp = (const char*)hat_l + sr * 256;
    const int sx = sr & 15;
    float d = 0.f;
    #pragma unroll
    for (int j = 0; j < 8; j++) {
      uint4 v = *(const uint4*)(rowp + (((hh * 8 + j) ^ sx) << 4));
      float4 qa = cq4[hh * 16 + 2 * j];
      float4 qb = cq4[hh * 16 + 2 * j + 1];
      d += bflo(v.x) * qa.x + bfhi(v.x) * qa.y
         + bflo(v.y) * qa.z + bfhi(v.y) * qa.w
         + bflo(v.z) * qb.x + bfhi(v.z) * qb.y
         + bflo(v.w) * qb.z + bfhi(v.w) * qb.w;
    }
    d += __shfl_xor(d, 1);
    if (hh == 0) {
      float* p = cw + ((size_t)k * SS + sr) * BB + b;
      if (mode == 0) *p = d; else *p += d;
    }
  }
}

extern "C" void kernel_launch(void* const* d_in, const int* in_sizes, int n_in,
                              void* d_out, int out_size, void* d_ws, size_t ws_size,
                              hipStream_t stream) {
  const float* item_eb = (const float*)d_in[0];   // [B,S,H]
  const float* mask    = (const float*)d_in[1];   // [B,S]
  const float* w       = (const float*)d_in[2];   // [1,S,K*H,H]
  float* out = (float*)d_out;                     // [B,K,H]

  char* ws = (char*)d_ws;
  unsigned short* hat_bf = (unsigned short*)ws;        // 67.1 MB [B][K][S][H]
  float* cw  = (float*)(ws + 67108864);                // 1 MB [K][S][B]
  float* swb = (float*)(ws + 68157440);                // 1 MB [K][S][B]

  einsum_mfma<<<dim3(128, 4), 256, 0, stream>>>(item_eb, w, hat_bf);

  routing_k<<<dim3(BB, KK), 256, 0, stream>>>(hat_bf, mask, nullptr, cw, out, 0);
  softmax_k<<<dim3(SS, KK), 256, 0, stream>>>(cw, mask, swb);
  routing_k<<<dim3(BB, KK), 256, 0, stream>>>(hat_bf, mask, swb, cw, out, 1);
  softmax_k<<<dim3(SS, KK), 256, 0, stream>>>(cw, mask, swb);
  routing_k<<<dim3(BB, KK), 256, 0, stream>>>(hat_bf, mask, swb, cw, out, 2);
}

// Round 5
// 185.182 us; speedup vs baseline: 1.1084x; 1.1084x over previous
//
#include <hip/hip_runtime.h>
#include <math.h>

#define BB 512
#define SS 128
#define KK 4
#define HH 128
#define DD 512   // K*H

typedef __attribute__((ext_vector_type(8))) short bf16x8;
typedef __attribute__((ext_vector_type(4))) float f32x4;

__device__ __forceinline__ unsigned short f2bf(float f) {
  unsigned u = __float_as_uint(f);
  unsigned r = u + 0x7fffu + ((u >> 16) & 1u);   // RNE (no NaNs in this data)
  return (unsigned short)(r >> 16);
}
__device__ __forceinline__ ushort4 f2bf4(float4 v) {
  ushort4 o; o.x = f2bf(v.x); o.y = f2bf(v.y); o.z = f2bf(v.z); o.w = f2bf(v.w);
  return o;
}
__device__ __forceinline__ float bfhi(unsigned u) { return __uint_as_float(u & 0xffff0000u); }
__device__ __forceinline__ float bflo(unsigned u) { return __uint_as_float(u << 16); }

// ---------------------------------------------------------------------------
// hat[b][k][s][h'] = sum_h item[b][s][h] * w[s][k*HH+h'][h]
// EXACT R2-verified structure (best measured einsum, 43 µs): A tile staged to
// LDS once (bf16, XOR granules), 8 pipelined W-stage steps (4 d-tiles x 2
// K-halves) with register prefetch into double-buffered Wl. Only change vs
// R2: hat is written LINEAR (routing no longer DMAs, so no global swizzle).
// ---------------------------------------------------------------------------
__global__ __launch_bounds__(256) void einsum_mfma(
    const float* __restrict__ item,   // f32 [B][S][H]
    const float* __restrict__ w,      // f32 [S][D][H]
    unsigned short* __restrict__ hat) // bf16 [B][K][S][H], linear
{
  __shared__ unsigned short Al[128 * 128];     // 32 KB: rows = local b, 128 h
  __shared__ unsigned short Wl[2][128 * 64];   // 2 x 16 KB K-half buffers
  const int s  = blockIdx.x;
  const int b0 = blockIdx.y * 128;
  const int t  = threadIdx.x;
  const int lane = t & 63, wvq = t >> 6;
  const int qm = wvq & 1, qn = wvq >> 1;
  const int n16 = lane & 15, kq = lane >> 4;

  const float* Abase = item + ((size_t)b0 * SS + s) * HH;  // + r*(SS*HH)
  const float* Wbase = w + (size_t)s * DD * HH;            // + (d0+r)*HH

  // ---- prologue: issue A tile + W step-0 loads, convert, park ----
  const int ac = t & 31, ar0 = t >> 5;     // A: f4-col 0..31, row base 0..7
  const int wc = t & 15, wr0 = t >> 4;     // W: f4-col 0..15, row base 0..15
  float4 apre[16];
  #pragma unroll
  for (int j = 0; j < 16; ++j)
    apre[j] = *(const float4*)(Abase + (size_t)(ar0 + 8 * j) * (SS * HH) + ac * 4);
  float4 wpre[8];
  #pragma unroll
  for (int j = 0; j < 8; ++j)
    wpre[j] = *(const float4*)(Wbase + (size_t)(wr0 + 16 * j) * HH + wc * 4);

  #pragma unroll
  for (int j = 0; j < 16; ++j) {
    const int r = ar0 + 8 * j;
    const int lg = ac >> 1;                          // logical 16B granule 0..15
    *(ushort4*)&Al[r * 128 + ((lg ^ (r & 15)) * 8) + (ac & 1) * 4] = f2bf4(apre[j]);
  }
  #pragma unroll
  for (int j = 0; j < 8; ++j) {
    const int r = wr0 + 16 * j;
    *(ushort4*)&Wl[0][r * 64 + ((((wc >> 1) + r) & 7) * 8) + (wc & 1) * 4] = f2bf4(wpre[j]);
  }
  __syncthreads();

  int buf = 0;
  for (int dt = 0; dt < 4; ++dt) {
    f32x4 acc[4][4] = {};
    #pragma unroll
    for (int hs = 0; hs < 2; ++hs) {
      const int step = dt * 2 + hs;
      if (step < 7) {                                // issue next stage EARLY
        const int d0n = ((step + 1) >> 1) * 128;
        const int ksn = ((step + 1) & 1) * 64;
        #pragma unroll
        for (int j = 0; j < 8; ++j)
          wpre[j] = *(const float4*)(Wbase + (size_t)(d0n + wr0 + 16 * j) * HH + ksn + wc * 4);
      }
      #pragma unroll
      for (int kk = 0; kk < 2; ++kk) {
        bf16x8 af[4], bfr[4];
        #pragma unroll
        for (int i = 0; i < 4; ++i) {
          const int ra = qm * 64 + i * 16 + n16;     // w rows (h')
          const int rb = qn * 64 + i * 16 + n16;     // item rows (b)
          af[i]  = *(const bf16x8*)&Wl[buf][ra * 64 + ((kk * 4 + kq + ra) & 7) * 8];
          bfr[i] = *(const bf16x8*)&Al[rb * 128 + (((hs * 8 + kk * 4 + kq) ^ (rb & 15)) * 8)];
        }
        #pragma unroll
        for (int i = 0; i < 4; ++i)
          #pragma unroll
          for (int j = 0; j < 4; ++j)
            acc[i][j] = __builtin_amdgcn_mfma_f32_16x16x32_bf16(af[i], bfr[j], acc[i][j], 0, 0, 0);
      }
      if (step < 7) {                                // write LATE, one barrier
        #pragma unroll
        for (int j = 0; j < 8; ++j) {
          const int r = wr0 + 16 * j;
          *(ushort4*)&Wl[buf ^ 1][r * 64 + ((((wc >> 1) + r) & 7) * 8) + (wc & 1) * 4] = f2bf4(wpre[j]);
        }
        __syncthreads();
        buf ^= 1;
      }
    }
    // epilogue d-tile dt: row = qm*64+i*16+kq*4+reg = h'; col = qn*64+j*16+n16 = b
    #pragma unroll
    for (int j = 0; j < 4; ++j) {
      const int b = b0 + qn * 64 + j * 16 + n16;
      unsigned short* orow = hat + (((size_t)b * KK + dt) * SS + s) * HH;
      #pragma unroll
      for (int i = 0; i < 4; ++i) {
        const int h = qm * 64 + i * 16 + kq * 4;
        ushort4 o;
        o.x = f2bf(acc[i][j][0]); o.y = f2bf(acc[i][j][1]);
        o.z = f2bf(acc[i][j][2]); o.w = f2bf(acc[i][j][3]);
        *(ushort4*)(orow + h) = o;                   // LINEAR
      }
    }
  }
}

// ---------------------------------------------------------------------------
// Batch-axis softmax (legacy torch dim=0) + mask zeroing. Grid (S,K).
// ---------------------------------------------------------------------------
__global__ __launch_bounds__(256) void softmax_k(
    const float* __restrict__ cw, const float* __restrict__ mask,
    float* __restrict__ sw)
{
  __shared__ float rbuf[4];
  const int s = blockIdx.x, k = blockIdx.y, t = threadIdx.x;
  const size_t base = ((size_t)k * SS + s) * BB;
  float v0 = cw[base + t], v1 = cw[base + 256 + t];
  float m = fmaxf(v0, v1);
  #pragma unroll
  for (int o = 32; o; o >>= 1) m = fmaxf(m, __shfl_xor(m, o));
  if ((t & 63) == 0) rbuf[t >> 6] = m;
  __syncthreads();
  m = fmaxf(fmaxf(rbuf[0], rbuf[1]), fmaxf(rbuf[2], rbuf[3]));
  float e0 = expf(v0 - m), e1 = expf(v1 - m);
  float ssum = e0 + e1;
  #pragma unroll
  for (int o = 32; o; o >>= 1) ssum += __shfl_xor(ssum, o);
  __syncthreads();
  if ((t & 63) == 0) rbuf[t >> 6] = ssum;
  __syncthreads();
  float inv = 1.f / (rbuf[0] + rbuf[1] + rbuf[2] + rbuf[3]);
  float m0 = mask[(size_t)t * SS + s];
  float m1 = mask[(size_t)(t + 256) * SS + s];
  sw[base + t]       = (m0 == 0.f) ? 0.f : e0 * inv;
  sw[base + 256 + t] = (m1 == 0.f) ? 0.f : e1 * inv;
}

// ---------------------------------------------------------------------------
// One routing iteration per (b,k). NO LDS SLAB: the 32 KB hat slab is read
// directly from global (phase 1: coalesced 256 B row segments, first touch;
// phase 2: re-read hits L2 — 32 blocks/XCD x 32 KB = 1 MB << 4 MB). LDS use
// drops to ~5 KB -> 8 blocks/CU, 32 waves = full occupancy; loads are
// ordinary TLP-hidden global reads (no serial DMA-then-wait).
//   mode 0: uniform sw from mask, cw  = delta
//   mode 1: sw from sw_in,        cw += delta
//   mode 2: sw from sw_in,        out = squash(cap)
// ---------------------------------------------------------------------------
__global__ __launch_bounds__(256) void routing_k(
    const unsigned short* __restrict__ hat, const float* __restrict__ mask,
    const float* __restrict__ sw_in, float* __restrict__ cw,
    float* __restrict__ out, int mode)
{
  __shared__ float sw_l[128];
  __shared__ float4 red4[8][32];
  __shared__ float4 cq4[32];
  const int b = blockIdx.x, k = blockIdx.y, t = threadIdx.x;

  if (t < 128) {
    sw_l[t] = (mode == 0)
      ? ((mask[(size_t)b * SS + t] == 0.f) ? 0.f : (1.f / 512.f))
      : sw_in[((size_t)k * SS + t) * BB + b];
  }
  __syncthreads();

  const unsigned short* slab = hat + ((size_t)b * KK + k) * SS * HH;

  // phase 1: cap[h] = sum_s sw[s]*hat[s][h]; thread (sg,h4) -> rows
  // sg*16..+15, shorts h4*4..+3 (8 B). Wave reads two 256 B row segments/iter.
  {
    const int h4 = t & 31, sg = t >> 5;
    float4 a = make_float4(0.f, 0.f, 0.f, 0.f);
    #pragma unroll
    for (int i = 0; i < 16; i++) {
      const int sr = sg * 16 + i;
      uint2 v = *(const uint2*)(slab + (size_t)sr * HH + h4 * 4);
      float ww = sw_l[sr];
      a.x = fmaf(ww, bflo(v.x), a.x);
      a.y = fmaf(ww, bfhi(v.x), a.y);
      a.z = fmaf(ww, bflo(v.y), a.z);
      a.w = fmaf(ww, bfhi(v.y), a.w);
    }
    red4[sg][h4] = a;
  }
  __syncthreads();

  if (t < 32) {
    float4 cap = red4[0][t];
    #pragma unroll
    for (int sg = 1; sg < 8; sg++) {
      float4 r = red4[sg][t];
      cap.x += r.x; cap.y += r.y; cap.z += r.z; cap.w += r.w;
    }
    float sq = cap.x * cap.x + cap.y * cap.y + cap.z * cap.z + cap.w * cap.w;
    #pragma unroll
    for (int o = 16; o; o >>= 1) sq += __shfl_xor(sq, o);
    const float n = sq;
    const float fac = n / (1.f + n) / sqrtf(n + 1e-9f);
    cap.x *= fac; cap.y *= fac; cap.z *= fac; cap.w *= fac;
    cq4[t] = cap;
    if (mode == 2)
      ((float4*)(out + ((size_t)b * KK + k) * HH))[t] = cap;
  }

  if (mode < 2) {
    __syncthreads();
    // phase 2: delta[s] = dot(hat[s][:], cq) — lane pair per s, L2-hot rows
    const int sr = t >> 1, hh = t & 1;
    const uint4* rowp = (const uint4*)(slab + (size_t)sr * HH + hh * 64);
    float d = 0.f;
    #pragma unroll
    for (int j = 0; j < 8; j++) {
      uint4 v = rowp[j];
      float4 qa = cq4[hh * 16 + 2 * j];
      float4 qb = cq4[hh * 16 + 2 * j + 1];
      d += bflo(v.x) * qa.x + bfhi(v.x) * qa.y
         + bflo(v.y) * qa.z + bfhi(v.y) * qa.w
         + bflo(v.z) * qb.x + bfhi(v.z) * qb.y
         + bflo(v.w) * qb.z + bfhi(v.w) * qb.w;
    }
    d += __shfl_xor(d, 1);
    if (hh == 0) {
      float* p = cw + ((size_t)k * SS + sr) * BB + b;
      if (mode == 0) *p = d; else *p += d;
    }
  }
}

extern "C" void kernel_launch(void* const* d_in, const int* in_sizes, int n_in,
                              void* d_out, int out_size, void* d_ws, size_t ws_size,
                              hipStream_t stream) {
  const float* item_eb = (const float*)d_in[0];   // [B,S,H]
  const float* mask    = (const float*)d_in[1];   // [B,S]
  const float* w       = (const float*)d_in[2];   // [1,S,K*H,H]
  float* out = (float*)d_out;                     // [B,K,H]

  char* ws = (char*)d_ws;
  unsigned short* hat_bf = (unsigned short*)ws;        // 67.1 MB [B][K][S][H]
  float* cw  = (float*)(ws + 67108864);                // 1 MB [K][S][B]
  float* swb = (float*)(ws + 68157440);                // 1 MB [K][S][B]

  einsum_mfma<<<dim3(128, 4), 256, 0, stream>>>(item_eb, w, hat_bf);

  routing_k<<<dim3(BB, KK), 256, 0, stream>>>(hat_bf, mask, nullptr, cw, out, 0);
  softmax_k<<<dim3(SS, KK), 256, 0, stream>>>(cw, mask, swb);
  routing_k<<<dim3(BB, KK), 256, 0, stream>>>(hat_bf, mask, swb, cw, out, 1);
  softmax_k<<<dim3(SS, KK), 256, 0, stream>>>(cw, mask, swb);
  routing_k<<<dim3(BB, KK), 256, 0, stream>>>(hat_bf, mask, swb, cw, out, 2);
}